// Round 5
// baseline (239.700 us; speedup 1.0000x reference)
//
#include <hip/hip_runtime.h>

// emb lookup -> RNN tanh(xp_t + h @ W_hh^T) over S=128 -> 5-class head.
// B=4096, S=128, D=256, VOCAB=50000. Floats f32, x int32, out f32.
//
// Phase 0 (R11): P[v] = bf16(emb[v] @ W_ih^T + b_ih + b_hh) via global_load_lds.
//   Evidence: three structurally different emb versions (R0/R1/R4) all land at
//   ~97-125us for a 77MB/12us job, with profiled counters showing the GPU EMPTY
//   (VALUBusy 0.36%, Occ 0.49%) -> latency-exposed with near-zero memory-level
//   parallelism. Register-prefetch can't fix it (needs ~20KB/CU in flight,
//   VGPR-impossible). global_load_lds holds in-flight data at zero VGPR cost:
//   4 LDS f32 buffers, DMA issued 2 tiles ahead (1 inst = 1 row = 64 lanes x
//   16B coalesced), counted vmcnt waits (0/16/32 = 16*min(i,2); exact-count
//   proof includes the 16 b16 g_P stores/iter; safe at all tails), lgkm-only
//   barrier. bf16 cvt moved after LDS read -> bit-identical g_P.
// Phase 1: EXACT R0 rnn (132us, stable). Verified local-opt vs 4 perturbations
//   (lgkm barrier neutral; 4-wave regressed; 2-block/CU never co-resided).

typedef __attribute__((ext_vector_type(8))) short bf16x8;   // 8 bf16 = 4 VGPRs
typedef __attribute__((ext_vector_type(4))) float f32x4;    // MFMA 16x16 accumulator

#define VOCAB 50000
#define NBLK_EMB 512
#define NTILES 3125

__device__ __align__(256) unsigned short g_P[VOCAB * 256];  // 25.6 MB projected table

static __device__ __forceinline__ float bf2f(unsigned short u) {
    union { unsigned int i; float f; } v; v.i = ((unsigned int)u) << 16; return v.f;
}
static __device__ __forceinline__ float bfbits2f(unsigned int zext_u16) {
    union { unsigned int i; float f; } v; v.i = zext_u16 << 16; return v.f;
}
static __device__ __forceinline__ unsigned short f2bf_rne(float f) {
    union { float f; unsigned int i; } v; v.f = f;
    unsigned int r = v.i + 0x7FFFu + ((v.i >> 16) & 1u);
    return (unsigned short)(r >> 16);
}
static __device__ __forceinline__ unsigned short f2bf_fast(float f) {   // round-half-up
    union { float f; unsigned int i; } v; v.f = f;
    return (unsigned short)((v.i + 0x8000u) >> 16);
}
static __device__ __forceinline__ bf16x8 cvt8(float4 a, float4 b) {
    bf16x8 r;
    r[0] = (short)f2bf_rne(a.x); r[1] = (short)f2bf_rne(a.y);
    r[2] = (short)f2bf_rne(a.z); r[3] = (short)f2bf_rne(a.w);
    r[4] = (short)f2bf_rne(b.x); r[5] = (short)f2bf_rne(b.y);
    r[6] = (short)f2bf_rne(b.z); r[7] = (short)f2bf_rne(b.w);
    return r;
}
static __device__ __forceinline__ bf16x8 load8_bf(const float* __restrict__ p) {
    return cvt8(((const float4*)p)[0], ((const float4*)p)[1]);
}
// tanh(x) = 1 - 2/(e^{2x}+1); med3 clamp keeps exp finite
static __device__ __forceinline__ float fast_tanh(float x) {
    x = __builtin_amdgcn_fmed3f(x, -8.f, 8.f);
    float e = __expf(2.f * x);
    return __builtin_fmaf(-2.f, __builtin_amdgcn_rcpf(e + 1.f), 1.f);
}
// Workgroup barrier that does NOT drain vmcnt: only LDS ops must be visible.
static __device__ __forceinline__ void barrier_lds_only() {
    asm volatile("s_waitcnt lgkmcnt(0)\n\ts_barrier" ::: "memory");
}

// ---------------- Phase 0: P = bf16(emb @ W_ih^T + (b_ih + b_hh)) ----------------
// 512 blocks x 256 thr (4 waves x 64 output cols). Tiles b, b+512, ... (<=7).
// stage[4][16][260]: 4 f32 tile buffers, rows padded to 260 dwords so the
// ds_read_b128 pattern (lane (l15,quad) reads row l15, dwords quad*8+kt*32..+8)
// is bank-uniform: start bank = (4*l15 + 8*quad) mod 32, 8 dwords/bank exactly.
// DMA: one global_load_lds(16B) per row per wave = 64 lanes x 16B -> linear 1KB
// row (pad bytes untouched). Counted-wait proof (per-wave vm program order is
// walled by asm memory clobbers): after L(i) come S(i-2),L(i+1),S(i-1),L(i+2)
// = 40 ops steady / 32 at tail; vmcnt(16*min(i,2)) <= true count always, and
// at every tail the suffix bound still covers L(i). Buffer reuse: DMA(i+2)
// overwrites the buffer read at iter i-2, drained at barrier(i-1)'s lgkmcnt(0).
__global__ __launch_bounds__(256)
void emb_proj_kernel(const float* __restrict__ emb,
                     const float* __restrict__ W_ih,
                     const float* __restrict__ b_ih,
                     const float* __restrict__ b_hh)
{
    __shared__ __align__(1024) float stage[4][16][260];
    const int tid  = threadIdx.x;
    const int lane = tid & 63;
    const int wid  = tid >> 6;
    const int n0   = wid * 64;
    const int l15  = lane & 15;
    const int quad = lane >> 4;

    // W_ih fragments + bias FIRST (these vm loads stay older than all DMAs,
    // so they never perturb the counted waits).
    bf16x8 wf[4][8];
    float  bias[4];
    #pragma unroll
    for (int nt = 0; nt < 4; ++nt) {
        int n = n0 + nt * 16 + l15;
        bias[nt] = b_ih[n] + b_hh[n];
        #pragma unroll
        for (int kt = 0; kt < 8; ++kt)
            wf[nt][kt] = load8_bf(W_ih + n * 256 + quad * 8 + kt * 32);
    }

    const int b = blockIdx.x;

    // DMA issue: 4 rows per wave, 1 instruction per row (64 lanes x 16B).
    auto issue = [&](int t, int j) {
        if (t < NTILES) {
            #pragma unroll
            for (int rr = 0; rr < 4; ++rr) {
                int row = wid * 4 + rr;
                const float* g = emb + ((size_t)t * 16 + row) * 256 + lane * 4;
                __builtin_amdgcn_global_load_lds(
                    (const __attribute__((address_space(1))) void*)g,
                    (__attribute__((address_space(3))) void*)&stage[j][row][0],
                    16, 0, 0);
            }
        }
    };

    issue(b,            0);   // tile i=0
    issue(b + NBLK_EMB, 1);   // tile i=1

    #pragma unroll
    for (int i = 0; i < 7; ++i) {
        int tile = b + i * NBLK_EMB;
        if (tile < NTILES) {
            issue(b + (i + 2) * NBLK_EMB, (i + 2) & 3);
            if (i == 0)      asm volatile("s_waitcnt vmcnt(0)"  ::: "memory");
            else if (i == 1) asm volatile("s_waitcnt vmcnt(16)" ::: "memory");
            else             asm volatile("s_waitcnt vmcnt(32)" ::: "memory");
            barrier_lds_only();   // all waves' tile-i DMAs visible; prior reads drained

            f32x4 acc[4];
            #pragma unroll
            for (int nt = 0; nt < 4; ++nt) acc[nt] = (f32x4){0.f, 0.f, 0.f, 0.f};
            #pragma unroll
            for (int kt = 0; kt < 8; ++kt) {
                float4 u = *(const float4*)&stage[i & 3][l15][quad * 8 + kt * 32];
                float4 v = *(const float4*)&stage[i & 3][l15][quad * 8 + kt * 32 + 4];
                bf16x8 a = cvt8(u, v);
                #pragma unroll
                for (int nt = 0; nt < 4; ++nt)
                    acc[nt] = __builtin_amdgcn_mfma_f32_16x16x32_bf16(a, wf[nt][kt], acc[nt], 0, 0, 0);
            }
            // direct store: C row = tile*16 + quad*4 + r, col = n0 + nt*16 + l15.
            // Exactly 16 b16 stores/thread (non-mergeable: 32B-strided) — the
            // counted-wait proof depends on this count.
            unsigned short* prow = g_P + ((size_t)tile * 16 + quad * 4) * 256 + n0;
            #pragma unroll
            for (int nt = 0; nt < 4; ++nt) {
                #pragma unroll
                for (int r = 0; r < 4; ++r)
                    prow[r * 256 + nt * 16 + l15] = f2bf_rne(acc[nt][r] + bias[nt]);
            }
        }
    }
}

// ---------------- Phase 1: recurrence + classifier (EXACT R0 best, 132us) ----------------
// h LDS layout (per 8KB buffer): element (row m, col c) at byte
//   m*512 + (((c>>3) ^ m) << 4) + (c&7)*2      (granule-XOR swizzle, conflict-free writes)
__global__ __launch_bounds__(512, 2)
void rnn_kernel(const int* __restrict__ x,
                const float* __restrict__ W_hh,
                const float* __restrict__ W_cls,
                const float* __restrict__ b_cls,
                float* __restrict__ out)
{
    __shared__ __align__(16) unsigned short h_lds[2][16 * 256];  // 2 x 8 KB
    __shared__ __align__(16) int tok_t[128 * 16];                // [t][row]
    __shared__ __align__(16) float wcls_lds[5 * 256];
    __shared__ float bcls_lds[5];

    const int tid  = threadIdx.x;
    const int lane = tid & 63;
    const int wid  = tid >> 6;          // 8 waves
    const int b0   = blockIdx.x * 16;
    const int n0   = wid * 32;          // wave's 32-col slice
    const int l15  = lane & 15;
    const int quad = lane >> 4;

    // W_hh -> bf16 B-fragments, VGPR-resident
    bf16x8 wf[2][8];
    #pragma unroll
    for (int nt = 0; nt < 2; ++nt) {
        int n = n0 + nt * 16 + l15;
        #pragma unroll
        for (int kt = 0; kt < 8; ++kt)
            wf[nt][kt] = load8_bf(W_hh + n * 256 + quad * 8 + kt * 32);
    }

    // stage tokens transposed: tok_t[t*16 + row]
    {
        int row = tid & 15, tq = tid >> 4;   // tq 0..31
        int4 v = *(const int4*)(x + (size_t)(b0 + row) * 128 + tq * 4);
        tok_t[(tq * 4 + 0) * 16 + row] = v.x;
        tok_t[(tq * 4 + 1) * 16 + row] = v.y;
        tok_t[(tq * 4 + 2) * 16 + row] = v.z;
        tok_t[(tq * 4 + 3) * 16 + row] = v.w;
    }
    if (tid < 320) ((float4*)wcls_lds)[tid] = ((const float4*)W_cls)[tid];
    if (tid < 5)   bcls_lds[tid] = b_cls[tid];
    #pragma unroll
    for (int i = 0; i < 4; ++i) ((unsigned int*)h_lds[0])[tid + i * 512] = 0;

    // precomputed LDS byte offsets (loop-invariant; buf1 = +8192 imm)
    int aoff[8];
    #pragma unroll
    for (int kt = 0; kt < 8; ++kt)
        aoff[kt] = l15 * 512 + (((quad + 4 * kt) ^ l15) << 4);
    int woff[8];   // [nt*4 + r]
    #pragma unroll
    for (int nt = 0; nt < 2; ++nt)
        #pragma unroll
        for (int r = 0; r < 4; ++r) {
            int row = quad * 4 + r;
            int g   = (n0 >> 3) + nt * 2 + (l15 >> 3);
            woff[nt * 4 + r] = row * 512 + ((g ^ row) << 4) + (l15 & 7) * 2;
        }

    const unsigned int colByte = (unsigned int)(n0 + l15) * 2;   // within a g_P row

    // prologue: gather xp(t=0) -> gA, xp(t=1) -> gB (C-layout: row quad*4+r, col n0+nt*16+l15)
    unsigned int gA[8], gB[8];
    #pragma unroll
    for (int r = 0; r < 4; ++r) {
        const int* xr = x + (size_t)(b0 + quad * 4 + r) * 128;
        const unsigned short* p0 = g_P + (size_t)xr[0] * 256 + n0 + l15;
        const unsigned short* p1 = g_P + (size_t)xr[1] * 256 + n0 + l15;
        gA[r] = p0[0]; gA[4 + r] = p0[16];
        gB[r] = p1[0]; gB[4 + r] = p1[16];
    }
    __syncthreads();

    char* const h0 = (char*)&h_lds[0][0];

    auto step = [&](const char* hA, char* hW, unsigned int* g, int t) {
        // consume g as MFMA C operand (xp pre-added for free)
        f32x4 acc0 = { bfbits2f(g[0]), bfbits2f(g[1]), bfbits2f(g[2]), bfbits2f(g[3]) };
        f32x4 acc1 = { bfbits2f(g[4]), bfbits2f(g[5]), bfbits2f(g[6]), bfbits2f(g[7]) };
        // refill g for t+2 (in flight across 2 barriers)
        if (t + 2 < 128) {
            int4 tk = *(const int4*)&tok_t[(t + 2) * 16 + quad * 4];
            const unsigned short* r0 = (const unsigned short*)((const char*)g_P + ((unsigned int)tk.x * 512 + colByte));
            const unsigned short* r1 = (const unsigned short*)((const char*)g_P + ((unsigned int)tk.y * 512 + colByte));
            const unsigned short* r2 = (const unsigned short*)((const char*)g_P + ((unsigned int)tk.z * 512 + colByte));
            const unsigned short* r3 = (const unsigned short*)((const char*)g_P + ((unsigned int)tk.w * 512 + colByte));
            g[0] = r0[0]; g[4] = r0[16];
            g[1] = r1[0]; g[5] = r1[16];
            g[2] = r2[0]; g[6] = r2[16];
            g[3] = r3[0]; g[7] = r3[16];
        }
        #pragma unroll
        for (int kt = 0; kt < 8; ++kt) {
            bf16x8 a = *(const bf16x8*)(hA + aoff[kt]);
            acc0 = __builtin_amdgcn_mfma_f32_16x16x32_bf16(a, wf[0][kt], acc0, 0, 0, 0);
            acc1 = __builtin_amdgcn_mfma_f32_16x16x32_bf16(a, wf[1][kt], acc1, 0, 0, 0);
        }
        #pragma unroll
        for (int r = 0; r < 4; ++r) {
            *(unsigned short*)(hW + woff[r])     = f2bf_fast(fast_tanh(acc0[r]));
            *(unsigned short*)(hW + woff[4 + r]) = f2bf_fast(fast_tanh(acc1[r]));
        }
    };

    #pragma unroll 1
    for (int t2 = 0; t2 < 64; ++t2) {
        step(h0,        h0 + 8192, gA, 2 * t2);      // read buf0, write buf1
        __syncthreads();
        step(h0 + 8192, h0,        gB, 2 * t2 + 1);  // read buf1, write buf0
        __syncthreads();
    }

    // final h in buf0. Classifier: 4 threads per (row,c), shuffle-reduce.
    if (tid < 320) {
        int q = tid & 3, p = tid >> 2;
        int row = p / 5, c = p - row * 5;
        float acc = 0.f;
        #pragma unroll
        for (int kk = 0; kk < 64; ++kk) {
            int k = q * 64 + kk;
            int off = row * 512 + ((((k >> 3) ^ row)) << 4) + (k & 7) * 2;
            acc += bf2f(*(const unsigned short*)(h0 + off)) * wcls_lds[c * 256 + k];
        }
        acc += __shfl_xor(acc, 1);
        acc += __shfl_xor(acc, 2);
        if (q == 0) out[(size_t)(b0 + row) * 5 + c] = acc + bcls_lds[c];
    }
}

extern "C" void kernel_launch(void* const* d_in, const int* in_sizes, int n_in,
                              void* d_out, int out_size, void* d_ws, size_t ws_size,
                              hipStream_t stream)
{
    const int*   x     = (const int*)d_in[0];
    const float* emb   = (const float*)d_in[1];
    const float* W_ih  = (const float*)d_in[2];
    const float* W_hh  = (const float*)d_in[3];
    const float* b_ih  = (const float*)d_in[4];
    const float* b_hh  = (const float*)d_in[5];
    const float* W_cls = (const float*)d_in[6];
    const float* b_cls = (const float*)d_in[7];
    float*       out   = (float*)d_out;
    (void)d_ws; (void)ws_size;

    emb_proj_kernel<<<NBLK_EMB, 256, 0, stream>>>(emb, W_ih, b_ih, b_hh);
    rnn_kernel<<<256, 512, 0, stream>>>(x, W_hh, W_cls, b_cls, out);
}

// Round 6
// 226.205 us; speedup vs baseline: 1.0597x; 1.0597x over previous
//
#include <hip/hip_runtime.h>

// emb lookup -> RNN tanh(xp_t + h @ W_hh^T) over S=128 -> 5-class head.
// B=4096, S=128, D=256, VOCAB=50000. Floats f32, x int32, out f32.
//
// Session model (R5 post-mortem): BOTH kernels are bound by L2-miss traffic at
// ~800-900 GB/s effective. emb: 77MB -> ~97us floor across 4 structures.
// rnn: FETCH 113MB / 132us = 878 GB/s; all variants' durations = bytes/BW
// (R2 810 GB/s slower, R3 473 GB/s 2x slower). MfmaUtil/VALUBusy are passengers.
//
// Phase 0: EXACT R0 emb (best measured ~97us). Direct-load (R1), reg-prefetch
//   (R4), global_load_lds pipeline (R5) all equal or worse -> BW-bound.
// Phase 1 (R12): test whether rnn's 878 GB/s is MLP-limited: gather prefetch
//   deepened 2->4 steps (gA..gD, 4-step-unrolled loop) + lgkm-only barriers
//   (T4: __syncthreads drains vmcnt(0) per step, capping depth at 1; R1 showed
//   lgkm-only ALONE is neutral — depth and counted waits must come together).
//   In-flight gathers/wave: 8 -> 16-24 (~2x Little's-law capacity).
//   Bit-identical arithmetic throughout.

typedef __attribute__((ext_vector_type(8))) short bf16x8;   // 8 bf16 = 4 VGPRs
typedef __attribute__((ext_vector_type(4))) float f32x4;    // MFMA 16x16 accumulator

#define VOCAB 50000
#define NBLK_EMB 256
#define LDS_STRIDE 264   // emb kernel staging only

__device__ __align__(256) unsigned short g_P[VOCAB * 256];  // 25.6 MB projected table

static __device__ __forceinline__ float bf2f(unsigned short u) {
    union { unsigned int i; float f; } v; v.i = ((unsigned int)u) << 16; return v.f;
}
static __device__ __forceinline__ float bfbits2f(unsigned int zext_u16) {
    union { unsigned int i; float f; } v; v.i = zext_u16 << 16; return v.f;
}
static __device__ __forceinline__ unsigned short f2bf_rne(float f) {
    union { float f; unsigned int i; } v; v.f = f;
    unsigned int r = v.i + 0x7FFFu + ((v.i >> 16) & 1u);
    return (unsigned short)(r >> 16);
}
static __device__ __forceinline__ unsigned short f2bf_fast(float f) {   // round-half-up
    union { float f; unsigned int i; } v; v.f = f;
    return (unsigned short)((v.i + 0x8000u) >> 16);
}
static __device__ __forceinline__ bf16x8 cvt8(float4 a, float4 b) {
    bf16x8 r;
    r[0] = (short)f2bf_rne(a.x); r[1] = (short)f2bf_rne(a.y);
    r[2] = (short)f2bf_rne(a.z); r[3] = (short)f2bf_rne(a.w);
    r[4] = (short)f2bf_rne(b.x); r[5] = (short)f2bf_rne(b.y);
    r[6] = (short)f2bf_rne(b.z); r[7] = (short)f2bf_rne(b.w);
    return r;
}
static __device__ __forceinline__ bf16x8 load8_bf(const float* __restrict__ p) {
    return cvt8(((const float4*)p)[0], ((const float4*)p)[1]);
}
// tanh(x) = 1 - 2/(e^{2x}+1); med3 clamp keeps exp finite
static __device__ __forceinline__ float fast_tanh(float x) {
    x = __builtin_amdgcn_fmed3f(x, -8.f, 8.f);
    float e = __expf(2.f * x);
    return __builtin_fmaf(-2.f, __builtin_amdgcn_rcpf(e + 1.f), 1.f);
}
// Workgroup barrier that does NOT drain vmcnt: only LDS ops must be visible.
// All cross-wave hazards in rnn are LDS<->LDS (h, tok_t, wcls); in-flight
// global gathers keep counted vmcnt waits at their consumption sites.
static __device__ __forceinline__ void barrier_lds_only() {
    asm volatile("s_waitcnt lgkmcnt(0)\n\ts_barrier" ::: "memory");
}

// ---------------- Phase 0: P = bf16(emb @ W_ih^T + (b_ih + b_hh)) ----------------
__global__ __launch_bounds__(256)
void emb_proj_kernel(const float* __restrict__ emb,
                     const float* __restrict__ W_ih,
                     const float* __restrict__ b_ih,
                     const float* __restrict__ b_hh)
{
    __shared__ __align__(16) unsigned short tin [16 * LDS_STRIDE];
    __shared__ __align__(16) unsigned short tout[16 * LDS_STRIDE];
    const int tid  = threadIdx.x;
    const int lane = tid & 63;
    const int wid  = tid >> 6;
    const int n0   = wid * 64;
    const int row  = tid >> 4, seg = tid & 15;

    bf16x8 wf[4][8];
    float  bias[4];
    #pragma unroll
    for (int nt = 0; nt < 4; ++nt) {
        int n = n0 + nt * 16 + (lane & 15);
        bias[nt] = b_ih[n] + b_hh[n];
        #pragma unroll
        for (int kt = 0; kt < 8; ++kt)
            wf[nt][kt] = load8_bf(W_ih + n * 256 + (lane >> 4) * 8 + kt * 32);
    }

    int tile = blockIdx.x;
    float4 a0, a1, a2, a3;
    {
        const float4* s = (const float4*)(emb + ((size_t)tile * 16 + row) * 256 + seg * 16);
        a0 = s[0]; a1 = s[1]; a2 = s[2]; a3 = s[3];
    }

    for (; tile < 3125; tile += NBLK_EMB) {
        *(bf16x8*)(&tin[row * LDS_STRIDE + seg * 16])     = cvt8(a0, a1);
        *(bf16x8*)(&tin[row * LDS_STRIDE + seg * 16 + 8]) = cvt8(a2, a3);
        int tn = tile + NBLK_EMB;
        if (tn < 3125) {
            const float4* s = (const float4*)(emb + ((size_t)tn * 16 + row) * 256 + seg * 16);
            a0 = s[0]; a1 = s[1]; a2 = s[2]; a3 = s[3];
        }
        __syncthreads();   // B1: tin visible

        f32x4 acc[4];
        #pragma unroll
        for (int nt = 0; nt < 4; ++nt) acc[nt] = (f32x4){0.f, 0.f, 0.f, 0.f};
        #pragma unroll
        for (int kt = 0; kt < 8; ++kt) {
            bf16x8 a = *(bf16x8*)(&tin[(lane & 15) * LDS_STRIDE + (lane >> 4) * 8 + kt * 32]);
            #pragma unroll
            for (int nt = 0; nt < 4; ++nt)
                acc[nt] = __builtin_amdgcn_mfma_f32_16x16x32_bf16(a, wf[nt][kt], acc[nt], 0, 0, 0);
        }
        #pragma unroll
        for (int nt = 0; nt < 4; ++nt) {
            int n = n0 + nt * 16 + (lane & 15);
            #pragma unroll
            for (int r = 0; r < 4; ++r)
                tout[((lane >> 4) * 4 + r) * LDS_STRIDE + n] = f2bf_rne(acc[nt][r] + bias[nt]);
        }
        __syncthreads();   // B2: tout complete, tin reads complete
        {
            uint4 o0 = *(uint4*)(&tout[row * LDS_STRIDE + seg * 16]);
            uint4 o1 = *(uint4*)(&tout[row * LDS_STRIDE + seg * 16 + 8]);
            uint4* dst = (uint4*)(g_P + ((size_t)tile * 16 + row) * 256 + seg * 16);
            dst[0] = o0; dst[1] = o1;
        }
    }
}

// ---------------- Phase 1: recurrence + classifier ----------------
// h LDS layout (per 8KB buffer): element (row m, col c) at byte
//   m*512 + (((c>>3) ^ m) << 4) + (c&7)*2      (granule-XOR swizzle, conflict-free writes)
__global__ __launch_bounds__(512, 2)
void rnn_kernel(const int* __restrict__ x,
                const float* __restrict__ W_hh,
                const float* __restrict__ W_cls,
                const float* __restrict__ b_cls,
                float* __restrict__ out)
{
    __shared__ __align__(16) unsigned short h_lds[2][16 * 256];  // 2 x 8 KB
    __shared__ __align__(16) int tok_t[128 * 16];                // [t][row]
    __shared__ __align__(16) float wcls_lds[5 * 256];
    __shared__ float bcls_lds[5];

    const int tid  = threadIdx.x;
    const int lane = tid & 63;
    const int wid  = tid >> 6;          // 8 waves
    const int b0   = blockIdx.x * 16;
    const int n0   = wid * 32;          // wave's 32-col slice
    const int l15  = lane & 15;
    const int quad = lane >> 4;

    // W_hh -> bf16 B-fragments, VGPR-resident
    bf16x8 wf[2][8];
    #pragma unroll
    for (int nt = 0; nt < 2; ++nt) {
        int n = n0 + nt * 16 + l15;
        #pragma unroll
        for (int kt = 0; kt < 8; ++kt)
            wf[nt][kt] = load8_bf(W_hh + n * 256 + quad * 8 + kt * 32);
    }

    // stage tokens transposed: tok_t[t*16 + row]
    {
        int row = tid & 15, tq = tid >> 4;   // tq 0..31
        int4 v = *(const int4*)(x + (size_t)(b0 + row) * 128 + tq * 4);
        tok_t[(tq * 4 + 0) * 16 + row] = v.x;
        tok_t[(tq * 4 + 1) * 16 + row] = v.y;
        tok_t[(tq * 4 + 2) * 16 + row] = v.z;
        tok_t[(tq * 4 + 3) * 16 + row] = v.w;
    }
    if (tid < 320) ((float4*)wcls_lds)[tid] = ((const float4*)W_cls)[tid];
    if (tid < 5)   bcls_lds[tid] = b_cls[tid];
    #pragma unroll
    for (int i = 0; i < 4; ++i) ((unsigned int*)h_lds[0])[tid + i * 512] = 0;

    // precomputed LDS byte offsets (loop-invariant; buf1 = +8192 imm)
    int aoff[8];
    #pragma unroll
    for (int kt = 0; kt < 8; ++kt)
        aoff[kt] = l15 * 512 + (((quad + 4 * kt) ^ l15) << 4);
    int woff[8];   // [nt*4 + r]
    #pragma unroll
    for (int nt = 0; nt < 2; ++nt)
        #pragma unroll
        for (int r = 0; r < 4; ++r) {
            int row = quad * 4 + r;
            int g   = (n0 >> 3) + nt * 2 + (l15 >> 3);
            woff[nt * 4 + r] = row * 512 + ((g ^ row) << 4) + (l15 & 7) * 2;
        }

    const unsigned int colByte = (unsigned int)(n0 + l15) * 2;   // within a g_P row

    // prologue: gather xp(t=0..3) -> gA..gD (C-layout: row quad*4+r, col n0+nt*16+l15).
    // 4-step-deep pipeline: 16-24 gather loads in flight per wave, surviving
    // across lgkm-only barriers (T4) — ~2x Little's-law capacity vs 2-deep.
    unsigned int gA[8], gB[8], gC[8], gD[8];
    #pragma unroll
    for (int r = 0; r < 4; ++r) {
        const int* xr = x + (size_t)(b0 + quad * 4 + r) * 128;
        const unsigned short* p0 = g_P + (size_t)xr[0] * 256 + n0 + l15;
        const unsigned short* p1 = g_P + (size_t)xr[1] * 256 + n0 + l15;
        const unsigned short* p2 = g_P + (size_t)xr[2] * 256 + n0 + l15;
        const unsigned short* p3 = g_P + (size_t)xr[3] * 256 + n0 + l15;
        gA[r] = p0[0]; gA[4 + r] = p0[16];
        gB[r] = p1[0]; gB[4 + r] = p1[16];
        gC[r] = p2[0]; gC[4 + r] = p2[16];
        gD[r] = p3[0]; gD[4 + r] = p3[16];
    }
    barrier_lds_only();

    char* const h0 = (char*)&h_lds[0][0];

    auto step = [&](const char* hA, char* hW, unsigned int* g, int t) {
        // consume g as MFMA C operand (xp pre-added for free)
        f32x4 acc0 = { bfbits2f(g[0]), bfbits2f(g[1]), bfbits2f(g[2]), bfbits2f(g[3]) };
        f32x4 acc1 = { bfbits2f(g[4]), bfbits2f(g[5]), bfbits2f(g[6]), bfbits2f(g[7]) };
        // refill g for t+4 (in flight across 4 barriers; counted vmcnt at use)
        if (t + 4 < 128) {
            int4 tk = *(const int4*)&tok_t[(t + 4) * 16 + quad * 4];
            const unsigned short* r0 = (const unsigned short*)((const char*)g_P + ((unsigned int)tk.x * 512 + colByte));
            const unsigned short* r1 = (const unsigned short*)((const char*)g_P + ((unsigned int)tk.y * 512 + colByte));
            const unsigned short* r2 = (const unsigned short*)((const char*)g_P + ((unsigned int)tk.z * 512 + colByte));
            const unsigned short* r3 = (const unsigned short*)((const char*)g_P + ((unsigned int)tk.w * 512 + colByte));
            g[0] = r0[0]; g[4] = r0[16];
            g[1] = r1[0]; g[5] = r1[16];
            g[2] = r2[0]; g[6] = r2[16];
            g[3] = r3[0]; g[7] = r3[16];
        }
        #pragma unroll
        for (int kt = 0; kt < 8; ++kt) {
            bf16x8 a = *(const bf16x8*)(hA + aoff[kt]);
            acc0 = __builtin_amdgcn_mfma_f32_16x16x32_bf16(a, wf[0][kt], acc0, 0, 0, 0);
            acc1 = __builtin_amdgcn_mfma_f32_16x16x32_bf16(a, wf[1][kt], acc1, 0, 0, 0);
        }
        #pragma unroll
        for (int r = 0; r < 4; ++r) {
            *(unsigned short*)(hW + woff[r])     = f2bf_fast(fast_tanh(acc0[r]));
            *(unsigned short*)(hW + woff[4 + r]) = f2bf_fast(fast_tanh(acc1[r]));
        }
    };

    #pragma unroll 1
    for (int t4 = 0; t4 < 32; ++t4) {
        step(h0,        h0 + 8192, gA, 4 * t4);      // read buf0, write buf1
        barrier_lds_only();
        step(h0 + 8192, h0,        gB, 4 * t4 + 1);  // read buf1, write buf0
        barrier_lds_only();
        step(h0,        h0 + 8192, gC, 4 * t4 + 2);
        barrier_lds_only();
        step(h0 + 8192, h0,        gD, 4 * t4 + 3);
        barrier_lds_only();
    }

    // final h in buf0 (step 127 wrote buf0). Classifier: 4 threads per (row,c).
    if (tid < 320) {
        int q = tid & 3, p = tid >> 2;
        int row = p / 5, c = p - row * 5;
        float acc = 0.f;
        #pragma unroll
        for (int kk = 0; kk < 64; ++kk) {
            int k = q * 64 + kk;
            int off = row * 512 + ((((k >> 3) ^ row)) << 4) + (k & 7) * 2;
            acc += bf2f(*(const unsigned short*)(h0 + off)) * wcls_lds[c * 256 + k];
        }
        acc += __shfl_xor(acc, 1);
        acc += __shfl_xor(acc, 2);
        if (q == 0) out[(size_t)(b0 + row) * 5 + c] = acc + bcls_lds[c];
    }
}

extern "C" void kernel_launch(void* const* d_in, const int* in_sizes, int n_in,
                              void* d_out, int out_size, void* d_ws, size_t ws_size,
                              hipStream_t stream)
{
    const int*   x     = (const int*)d_in[0];
    const float* emb   = (const float*)d_in[1];
    const float* W_ih  = (const float*)d_in[2];
    const float* W_hh  = (const float*)d_in[3];
    const float* b_ih  = (const float*)d_in[4];
    const float* b_hh  = (const float*)d_in[5];
    const float* W_cls = (const float*)d_in[6];
    const float* b_cls = (const float*)d_in[7];
    float*       out   = (float*)d_out;
    (void)d_ws; (void)ws_size;

    emb_proj_kernel<<<NBLK_EMB, 256, 0, stream>>>(emb, W_ih, b_ih, b_hh);
    rnn_kernel<<<256, 512, 0, stream>>>(x, W_hh, W_cls, b_cls, out);
}